// Round 9
// baseline (371.704 us; speedup 1.0000x reference)
//
#include <hip/hip_runtime.h>
#include <hip/hip_bf16.h>
#include <hip/hip_fp16.h>

// Problem constants (from reference)
#define NODES 50000
#define NEDGE 800000
#define NE2   850000   // NEDGE + NODES self-loops
#define INDIM 128
#define F1    256      // HEADS*HID
#define HEADS 4
#define HID   64
#define OUTD  64
#define MTILES 3125    // NODES/16

// Bucketed CSR build (no global atomics)
#define NB   196       // buckets = ceil(NODES/256)
#define PB   196       // partition blocks
#define EPB  4096      // edges per partition block
#define CAP  6144      // per-bucket LDS sort capacity
#define G1B  782       // ceil(MTILES/4) gemm1 blocks in fused k_bg

typedef _Float16 f16;
typedef _Float16 f16x8 __attribute__((ext_vector_type(8)));
typedef _Float16 f16x4 __attribute__((ext_vector_type(4)));
typedef _Float16 f16x2 __attribute__((ext_vector_type(2)));
typedef float    f32x4 __attribute__((ext_vector_type(4)));

__device__ __forceinline__ float lrelu_exp(float e) {
    e = e > 0.f ? e : 0.2f * e;
    return __expf(e);
}

// ===== CSR pass 1: per-block LDS bucket histogram (+ W pre-swizzle blocks) ==
__global__ void k_hist(const int* __restrict__ ei, int* __restrict__ blkhist,
                       const float* __restrict__ W1, const float* __restrict__ W2,
                       f16* __restrict__ W1p, f16* __restrict__ W2p)
{
    const int b = blockIdx.x, t = threadIdx.x;
    if (b < PB) {
        __shared__ int h[NB];
        for (int i = t; i < NB; i += 256) h[i] = 0;
        __syncthreads();
        const int e0 = b * EPB;
        const int eend = min(e0 + EPB, NEDGE);
        for (int i = e0 + t; i < eend; i += 256) {
            int d = ei[NEDGE + i];
            atomicAdd(&h[d >> 8], 1);
        }
        __syncthreads();
        for (int i = t; i < NB; i += 256) blkhist[i * PB + b] = h[i];
    } else {
        int idx = (b - PB) * 256 + t;     // < 49152
        if (idx < 32768) {
            int j = idx & 7, l = (idx >> 3) & 63, fi = idx >> 9;
            int kb = fi & 3, ct = fi >> 2;
            int k = kb * 32 + (l >> 4) * 8 + j;
            int col = ct * 16 + (l & 15);
            W1p[idx] = (f16)W1[k * F1 + col];
        } else {
            int i2 = idx - 32768;         // < 16384
            int j = i2 & 7, l = (i2 >> 3) & 63, fi = i2 >> 9;
            int kb = fi & 7, ct = fi >> 3;
            int k = kb * 32 + (l >> 4) * 8 + j;
            int col = ct * 16 + (l & 15);
            W2p[i2] = (f16)W2[k * OUTD + col];
        }
    }
}

// ===== CSR pass 2 (scan folded): partition into bucket-ordered staging ======
__global__ void k_part(const int* __restrict__ ei, const int* __restrict__ blkhist,
                       int* __restrict__ rowtot, unsigned* __restrict__ staged)
{
    const int b = blockIdx.x, t = threadIdx.x;
    __shared__ int sS[256];
    __shared__ int cur[NB];
    int rowsum = 0, colpref = 0;
    if (t < NB) {
        const int* hrow = blkhist + t * PB;
        for (int p = 0; p < PB; ++p) {
            int h = hrow[p];
            colpref += (p < b) ? h : 0;
            rowsum += h;
        }
        if (b == 0) rowtot[t] = rowsum;   // publish for k_bg
    }
    sS[t] = (t < NB) ? rowsum : 0;
    __syncthreads();
    for (int off = 1; off < 256; off <<= 1) {
        int tv = (t >= off) ? sS[t - off] : 0;
        __syncthreads();
        sS[t] += tv;
        __syncthreads();
    }
    if (t < NB) cur[t] = (sS[t] - rowsum) + colpref;   // S[q] + col-prefix
    __syncthreads();
    const int e0 = b * EPB;
    const int eend = min(e0 + EPB, NEDGE);
    for (int i = e0 + t; i < eend; i += 256) {
        int sN = ei[i];
        int d  = ei[NEDGE + i];
        int pos = atomicAdd(&cur[d >> 8], 1);       // LDS atomic
        staged[pos] = (unsigned)sN | ((unsigned)(d & 255) << 16);
    }
}

// ===== FUSED pass 3 + layer-1 GEMM =========================================
// gemm1 writes xp1h in PLANE-MAJOR layout (8 planes of [N][32] f16) and the
// scores in head-major planes (ssrc[h*N+n]) so k_agg1s slices are line-pure.
__global__ __launch_bounds__(256) void k_bg(
    const unsigned* __restrict__ staged, const int* __restrict__ rowtot,
    int* __restrict__ row_ptr, int* __restrict__ csr_src,
    const float* __restrict__ x, const f16* __restrict__ W1p,
    const float* __restrict__ as1, const float* __restrict__ ad1,
    f16* __restrict__ xp1h, float* __restrict__ ssrc, float* __restrict__ sdst)
{
    if (blockIdx.x < NB) {
        __shared__ unsigned sorted2[CAP];   // 24 KB
        __shared__ int bin[256];
        __shared__ int cnt[256];
        __shared__ int sh[256];
        __shared__ int ssum[4];
        const int q = blockIdx.x, t = threadIdx.x;
        const int wv = t >> 6, lane = t & 63;
        int pv = (t < q) ? rowtot[t] : 0;
#pragma unroll
        for (int off = 32; off; off >>= 1) pv += __shfl_xor(pv, off);
        if (lane == 0) ssum[wv] = pv;
        cnt[t] = 0; bin[t] = 0;
        __syncthreads();
        const int estart = ssum[0] + ssum[1] + ssum[2] + ssum[3];
        const int m = rowtot[q];            // bucket edge count
        const int nodebase = q * 256;
        const int nn = min(256, NODES - nodebase);
        const int csrbase = estart + nodebase;

        const bool dosort = (m <= CAP);
        if (dosort) {
            for (int i = t; i < m; i += 256)
                atomicAdd(&bin[(staged[estart + i] & 0xFFFFu) >> 8], 1);
            __syncthreads();
            int bv = bin[t];
            sh[t] = bv;
            __syncthreads();
            for (int off = 1; off < 256; off <<= 1) {
                int tv = (t >= off) ? sh[t - off] : 0;
                __syncthreads();
                sh[t] += tv;
                __syncthreads();
            }
            bin[t] = sh[t] - bv;
            __syncthreads();
            for (int i = t; i < m; i += 256) {
                unsigned u = staged[estart + i];
                int p = atomicAdd(&bin[(u & 0xFFFFu) >> 8], 1);
                sorted2[p] = u;
            }
            __syncthreads();
        }

        if (dosort) {
            for (int i = t; i < m; i += 256)
                atomicAdd(&cnt[sorted2[i] >> 16], 1);
        } else {
            for (int i = t; i < m; i += 256)
                atomicAdd(&cnt[staged[estart + i] >> 16], 1);
        }
        __syncthreads();
        int v = cnt[t];
        sh[t] = v;
        __syncthreads();
        for (int off = 1; off < 256; off <<= 1) {
            int tv = (t >= off) ? sh[t - off] : 0;
            __syncthreads();
            sh[t] += tv;
            __syncthreads();
        }
        int excl = sh[t] - v;
        __syncthreads();
        if (t < nn) {
            int r = csrbase + excl + t;
            row_ptr[nodebase + t] = r;
            csr_src[r] = nodebase + t;      // self-loop in slot 0
            cnt[t] = excl + t + 1;
        }
        __syncthreads();
        if (dosort) {
            for (int i = t; i < m; i += 256) {
                unsigned u = sorted2[i];
                int pos = atomicAdd(&cnt[u >> 16], 1);
                csr_src[csrbase + pos] = (int)(u & 0xFFFFu);
            }
        } else {
            for (int i = t; i < m; i += 256) {
                unsigned u = staged[estart + i];
                int pos = atomicAdd(&cnt[u >> 16], 1);
                csr_src[csrbase + pos] = (int)(u & 0xFFFFu);
            }
        }
        if (q == NB - 1 && t == 0) row_ptr[NODES] = NE2;
        return;
    }

    // ---- gemm1 path ----
    const int wv = threadIdx.x >> 6, lane = threadIdx.x & 63;
    const int l15 = lane & 15, quad = lane >> 4;
    const int rowtile = (blockIdx.x - NB) * 4 + wv;
    if (rowtile >= MTILES) return;
    const int rowbase = rowtile * 16;

    f16x8 afrag[4];
    const float* xrow = x + (rowbase + l15) * INDIM + quad * 8;
#pragma unroll
    for (int kb = 0; kb < 4; ++kb) {
        float4 u0 = *(const float4*)(xrow + kb * 32);
        float4 u1 = *(const float4*)(xrow + kb * 32 + 4);
        f16x8 a;
        a[0] = (f16)u0.x; a[1] = (f16)u0.y; a[2] = (f16)u0.z; a[3] = (f16)u0.w;
        a[4] = (f16)u1.x; a[5] = (f16)u1.y; a[6] = (f16)u1.z; a[7] = (f16)u1.w;
        afrag[kb] = a;
    }

    const f16x8* Wf = (const f16x8*)W1p;
    f32x4 acc[16];
#pragma unroll
    for (int ct = 0; ct < 16; ++ct) acc[ct] = (f32x4){0.f, 0.f, 0.f, 0.f};
#pragma unroll
    for (int ct = 0; ct < 16; ++ct) {
#pragma unroll
        for (int kb = 0; kb < 4; ++kb) {
            f16x8 b = Wf[(ct * 4 + kb) * 64 + lane];
            acc[ct] = __builtin_amdgcn_mfma_f32_16x16x32_f16(afrag[kb], b, acc[ct], 0, 0, 0);
        }
    }
    // stores to PLANES: col = ct*16+l15; plane = ct>>1, within = (ct&1)*16+l15
    const int orow = rowbase + quad * 4;
#pragma unroll
    for (int ct = 0; ct < 16; ++ct) {
        f16* plane = xp1h + (size_t)(ct >> 1) * NODES * 32;
        const int cw = (ct & 1) * 16 + l15;
#pragma unroll
        for (int r = 0; r < 4; ++r)
            plane[(orow + r) * 32 + cw] = (f16)acc[ct][r];
    }
    float ps[4][4], pd[4][4];
#pragma unroll
    for (int h = 0; h < 4; ++h)
#pragma unroll
        for (int r = 0; r < 4; ++r) { ps[h][r] = 0.f; pd[h][r] = 0.f; }
#pragma unroll
    for (int ct = 0; ct < 16; ++ct) {
        float av = as1[ct * 16 + l15];
        float dv = ad1[ct * 16 + l15];
        int h = ct >> 2;
#pragma unroll
        for (int r = 0; r < 4; ++r) {
            ps[h][r] = fmaf(acc[ct][r], av, ps[h][r]);
            pd[h][r] = fmaf(acc[ct][r], dv, pd[h][r]);
        }
    }
#pragma unroll
    for (int off = 8; off; off >>= 1) {
#pragma unroll
        for (int h = 0; h < 4; ++h)
#pragma unroll
            for (int r = 0; r < 4; ++r) {
                ps[h][r] += __shfl_xor(ps[h][r], off);
                pd[h][r] += __shfl_xor(pd[h][r], off);
            }
    }
    if (l15 == 0) {
#pragma unroll
        for (int r = 0; r < 4; ++r) {
            int row = orow + r;
#pragma unroll
            for (int h = 0; h < 4; ++h) {
                ssrc[h * NODES + row] = ps[h][r];   // head-major planes
                sdst[h * NODES + row] = pd[h][r];
            }
        }
    }
}

// ===== Layer 1 aggregate, XCD-sliced: slice = blockIdx%8 -> XCD round-robin.
// Each slice owns a 3.2 MB channel plane (fits 4 MB per-XCD L2) -> random
// gathers become L2 hits. Wave = node; 8 groups x 8 lanes; 2 edges in flight.
__global__ __launch_bounds__(256) void k_agg1s(
    const int* __restrict__ row_ptr, const int* __restrict__ csr_src,
    const float* __restrict__ ssrc, const float* __restrict__ sdst,
    const f16* __restrict__ xp1h, const float* __restrict__ bias,
    f16* __restrict__ hbuf)
{
    const int wv = threadIdx.x >> 6, l = threadIdx.x & 63;
    const int slice = blockIdx.x & 7;
    const int n = (blockIdx.x >> 3) * 4 + wv;
    const int grp = l >> 3, sub = l & 7;
    const int h = slice >> 1;                    // head of this 32-ch slice
    const float sd = sdst[h * NODES + n];
    const int jbeg = row_ptr[n], jend = row_ptr[n + 1];
    const f16x4* xv = (const f16x4*)(xp1h + (size_t)slice * NODES * 32);
    const float* sc = ssrc + (size_t)h * NODES;

    float den = 0.f;
    float a0 = 0.f, a1 = 0.f, a2 = 0.f, a3 = 0.f;
    for (int e = jbeg + grp; e < jend; e += 16) {
        const int e2 = e + 8;
        const bool vb = (e2 < jend);
        int sa = __builtin_nontemporal_load(csr_src + e);
        int sb = vb ? __builtin_nontemporal_load(csr_src + e2) : 0;
        float sca = sc[sa];
        float scb = sc[sb];
        f16x4 va  = xv[sa * 8 + sub];
        f16x4 vbx = xv[sb * 8 + sub];
        float ea = lrelu_exp(sca + sd);
        float eb = vb ? lrelu_exp(scb + sd) : 0.f;
        den += ea + eb;
        a0 = fmaf(ea, (float)va[0], a0); a1 = fmaf(ea, (float)va[1], a1);
        a2 = fmaf(ea, (float)va[2], a2); a3 = fmaf(ea, (float)va[3], a3);
        a0 = fmaf(eb, (float)vbx[0], a0); a1 = fmaf(eb, (float)vbx[1], a1);
        a2 = fmaf(eb, (float)vbx[2], a2); a3 = fmaf(eb, (float)vbx[3], a3);
    }
    // butterfly over the 8 edge-groups (lane bits 3..5)
    den += __shfl_xor(den, 8); den += __shfl_xor(den, 16); den += __shfl_xor(den, 32);
    const float rd = 1.f / (den + 1e-16f);
    a0 += __shfl_xor(a0, 8); a0 += __shfl_xor(a0, 16); a0 += __shfl_xor(a0, 32);
    a1 += __shfl_xor(a1, 8); a1 += __shfl_xor(a1, 16); a1 += __shfl_xor(a1, 32);
    a2 += __shfl_xor(a2, 8); a2 += __shfl_xor(a2, 16); a2 += __shfl_xor(a2, 32);
    a3 += __shfl_xor(a3, 8); a3 += __shfl_xor(a3, 16); a3 += __shfl_xor(a3, 32);
    if (grp == 0) {
        const int cb = slice * 32 + sub * 4;
        float4 bb = *(const float4*)(bias + cb);
        f16x4 o;
        float v;
        v = fmaf(a0, rd, bb.x); o[0] = (f16)(v > 0.f ? v : 0.f);
        v = fmaf(a1, rd, bb.y); o[1] = (f16)(v > 0.f ? v : 0.f);
        v = fmaf(a2, rd, bb.z); o[2] = (f16)(v > 0.f ? v : 0.f);
        v = fmaf(a3, rd, bb.w); o[3] = (f16)(v > 0.f ? v : 0.f);
        *(f16x4*)(hbuf + (size_t)n * F1 + cb) = o;   // hbuf stays row-major
    }
}

// ====== Layer 2 GEMM (MFMA) + fused scores ================================
// Writes xp2h in PLANE-MAJOR (4 planes of [N][16] f16): col=ct*16+l15 ->
// plane ct, within l15. Scores stay flat [N].
__global__ __launch_bounds__(256) void k_gemm2m(
    const f16* __restrict__ hbuf, const f16* __restrict__ W2p,
    const float* __restrict__ as2, const float* __restrict__ ad2,
    f16* __restrict__ xp2h, float* __restrict__ ssrc, float* __restrict__ sdst)
{
    const int wv = threadIdx.x >> 6, lane = threadIdx.x & 63;
    const int l15 = lane & 15, quad = lane >> 4;
    const int rowtile = blockIdx.x * 4 + wv;
    if (rowtile >= MTILES) return;
    const int rowbase = rowtile * 16;

    const f16x8* Wf = (const f16x8*)W2p;
    f32x4 acc[4];
#pragma unroll
    for (int ct = 0; ct < 4; ++ct) acc[ct] = (f32x4){0.f, 0.f, 0.f, 0.f};
    const f16* hrow = hbuf + (rowbase + l15) * F1 + quad * 8;
#pragma unroll
    for (int kb = 0; kb < 8; ++kb) {
        f16x8 a = *(const f16x8*)(hrow + kb * 32);
#pragma unroll
        for (int ct = 0; ct < 4; ++ct) {
            f16x8 b = Wf[(ct * 8 + kb) * 64 + lane];
            acc[ct] = __builtin_amdgcn_mfma_f32_16x16x32_f16(a, b, acc[ct], 0, 0, 0);
        }
    }
    const int orow = rowbase + quad * 4;
#pragma unroll
    for (int ct = 0; ct < 4; ++ct) {
        f16* plane = xp2h + (size_t)ct * NODES * 16;
#pragma unroll
        for (int r = 0; r < 4; ++r)
            plane[(orow + r) * 16 + l15] = (f16)acc[ct][r];
    }
    float ps[4] = {0.f,0.f,0.f,0.f}, pd[4] = {0.f,0.f,0.f,0.f};
#pragma unroll
    for (int ct = 0; ct < 4; ++ct) {
        float av = as2[ct * 16 + l15];
        float dv = ad2[ct * 16 + l15];
#pragma unroll
        for (int r = 0; r < 4; ++r) {
            ps[r] = fmaf(acc[ct][r], av, ps[r]);
            pd[r] = fmaf(acc[ct][r], dv, pd[r]);
        }
    }
#pragma unroll
    for (int off = 8; off; off >>= 1) {
#pragma unroll
        for (int r = 0; r < 4; ++r) {
            ps[r] += __shfl_xor(ps[r], off);
            pd[r] += __shfl_xor(pd[r], off);
        }
    }
    if (l15 == 0) {
#pragma unroll
        for (int r = 0; r < 4; ++r) {
            ssrc[orow + r] = ps[r];
            sdst[orow + r] = pd[r];
        }
    }
}

// ===== Layer 2 aggregate, XCD-sliced: 4 slices x 16 ch (1.6 MB planes) =====
__global__ __launch_bounds__(256) void k_agg2s(
    const int* __restrict__ row_ptr, const int* __restrict__ csr_src,
    const float* __restrict__ ssrc, const float* __restrict__ sdst,
    const f16* __restrict__ xp2h, const float* __restrict__ bias,
    float* __restrict__ out)
{
    const int wv = threadIdx.x >> 6, l = threadIdx.x & 63;
    const int slice = blockIdx.x & 3;
    const int n = (blockIdx.x >> 2) * 4 + wv;
    const int grp = l >> 3, sub = l & 7;
    const float sd = sdst[n];
    const int jbeg = row_ptr[n], jend = row_ptr[n + 1];
    const f16x2* xv = (const f16x2*)(xp2h + (size_t)slice * NODES * 16);

    float den = 0.f;
    float a0 = 0.f, a1 = 0.f;
    for (int e = jbeg + grp; e < jend; e += 16) {
        const int e2 = e + 8;
        const bool vb = (e2 < jend);
        int sa = __builtin_nontemporal_load(csr_src + e);
        int sb = vb ? __builtin_nontemporal_load(csr_src + e2) : 0;
        float sca = ssrc[sa];
        float scb = ssrc[sb];
        f16x2 va  = xv[sa * 8 + sub];
        f16x2 vbx = xv[sb * 8 + sub];
        float ea = lrelu_exp(sca + sd);
        float eb = vb ? lrelu_exp(scb + sd) : 0.f;
        den += ea + eb;
        a0 = fmaf(ea, (float)va[0], a0); a1 = fmaf(ea, (float)va[1], a1);
        a0 = fmaf(eb, (float)vbx[0], a0); a1 = fmaf(eb, (float)vbx[1], a1);
    }
    den += __shfl_xor(den, 8); den += __shfl_xor(den, 16); den += __shfl_xor(den, 32);
    const float rd = 1.f / (den + 1e-16f);
    a0 += __shfl_xor(a0, 8); a0 += __shfl_xor(a0, 16); a0 += __shfl_xor(a0, 32);
    a1 += __shfl_xor(a1, 8); a1 += __shfl_xor(a1, 16); a1 += __shfl_xor(a1, 32);
    if (grp == 0) {
        const int cb = slice * 16 + sub * 2;
        float2 o;
        o.x = fmaf(a0, rd, bias[cb]);
        o.y = fmaf(a1, rd, bias[cb + 1]);
        *(float2*)(out + (size_t)n * OUTD + cb) = o;
    }
}

extern "C" void kernel_launch(void* const* d_in, const int* in_sizes, int n_in,
                              void* d_out, int out_size, void* d_ws, size_t ws_size,
                              hipStream_t stream)
{
    (void)in_sizes; (void)n_in; (void)out_size; (void)ws_size;
    const float* x   = (const float*)d_in[0];
    const int*   ei  = (const int*)d_in[1];
    const float* W1  = (const float*)d_in[2];
    const float* as1 = (const float*)d_in[3];
    const float* ad1 = (const float*)d_in[4];
    const float* b1  = (const float*)d_in[5];
    const float* W2  = (const float*)d_in[6];
    const float* as2 = (const float*)d_in[7];
    const float* ad2 = (const float*)d_in[8];
    const float* b2  = (const float*)d_in[9];
    float* out = (float*)d_out;

    // workspace layout (~61 MB)
    f16* xp1h    = (f16*)d_ws;                             // 8 planes [N][32] (25.6 MB)
    f16* hbuf    = xp1h + (size_t)NODES * F1;              // [N][256] (25.6 MB)
    f16* W1p     = hbuf + (size_t)NODES * F1;              // 32768 f16
    f16* W2p     = W1p + 32768;                            // 16384 f16
    float* ssrc1 = (float*)(W2p + 16384);                  // 4 planes [N]
    float* sdst1 = ssrc1 + (size_t)NODES * HEADS;          // 4 planes [N]
    float* ssrc2 = sdst1 + (size_t)NODES * HEADS;          // N
    float* sdst2 = ssrc2 + (size_t)NODES;                  // N
    int* row_ptr = (int*)(sdst2 + (size_t)NODES);          // N+1
    int* blkhist = row_ptr + NODES + 1;                    // NB*PB = 38416
    int* rowtot  = blkhist + NB * PB;                      // NB
    int* csr_src = rowtot + NB;                            // NE2
    unsigned* staged = (unsigned*)(csr_src + NE2);         // NEDGE (3.2 MB)
    f16* xp2h    = xp1h;   // alias: xp1h dead after k_agg1s (4 planes [N][16])

    // ---- CSR build: bucketed counting sort, zero global atomics ----
    k_hist<<<PB + 192, 256, 0, stream>>>(ei, blkhist, W1, W2, W1p, W2p);
    k_part<<<PB, 256, 0, stream>>>(ei, blkhist, rowtot, staged);

    // ---- fused: bucket CSR-finish || layer-1 GEMM ----
    k_bg<<<NB + G1B, 256, 0, stream>>>(staged, rowtot, row_ptr, csr_src,
                                       x, W1p, as1, ad1, xp1h, ssrc1, sdst1);

    // ---- layer 1 aggregate (XCD-sliced: 8 slices x 32 ch) ----
    k_agg1s<<<(NODES / 4) * 8, 256, 0, stream>>>(row_ptr, csr_src, ssrc1, sdst1,
                                                 xp1h, b1, hbuf);

    // ---- layer 2 ----
    k_gemm2m<<<(MTILES + 3) / 4, 256, 0, stream>>>(hbuf, W2p, as2, ad2,
                                                   xp2h, ssrc2, sdst2);
    // ---- layer 2 aggregate (XCD-sliced: 4 slices x 16 ch) ----
    k_agg2s<<<(NODES / 4) * 4, 256, 0, stream>>>(row_ptr, csr_src, ssrc2, sdst2,
                                                 xp2h, b2, out);
}

// Round 10
// 228.508 us; speedup vs baseline: 1.6267x; 1.6267x over previous
//
#include <hip/hip_runtime.h>
#include <hip/hip_bf16.h>
#include <hip/hip_fp16.h>

// Problem constants (from reference)
#define NODES 50000
#define NEDGE 800000
#define NE2   850000   // NEDGE + NODES self-loops
#define INDIM 128
#define F1    256      // HEADS*HID
#define HEADS 4
#define HID   64
#define OUTD  64
#define MTILES 3125    // NODES/16

// Bucketed CSR build (no global atomics)
#define NB   196       // buckets = ceil(NODES/256)
#define PB   196       // partition blocks
#define EPB  4096      // edges per partition block
#define G1B  782       // ceil(MTILES/4) gemm1 blocks in fused k_bg

typedef _Float16 f16;
typedef _Float16 f16x8 __attribute__((ext_vector_type(8)));
typedef float    f32x4 __attribute__((ext_vector_type(4)));

__device__ __forceinline__ float lrelu_exp(float e) {
    e = e > 0.f ? e : 0.2f * e;
    return __expf(e);
}

// ===== CSR pass 1: per-block LDS bucket histogram (+ W pre-swizzle blocks) ==
__global__ void k_hist(const int* __restrict__ ei, int* __restrict__ blkhist,
                       const float* __restrict__ W1, const float* __restrict__ W2,
                       f16* __restrict__ W1p, f16* __restrict__ W2p)
{
    const int b = blockIdx.x, t = threadIdx.x;
    if (b < PB) {
        __shared__ int h[NB];
        for (int i = t; i < NB; i += 256) h[i] = 0;
        __syncthreads();
        const int e0 = b * EPB;
        const int eend = min(e0 + EPB, NEDGE);
        for (int i = e0 + t; i < eend; i += 256) {
            int d = ei[NEDGE + i];
            atomicAdd(&h[d >> 8], 1);
        }
        __syncthreads();
        // [bucket][block] layout (RAW counts)
        for (int i = t; i < NB; i += 256) blkhist[i * PB + b] = h[i];
    } else {
        int idx = (b - PB) * 256 + t;     // < 49152
        if (idx < 32768) {
            int j = idx & 7, l = (idx >> 3) & 63, fi = idx >> 9;
            int kb = fi & 3, ct = fi >> 2;
            int k = kb * 32 + (l >> 4) * 8 + j;
            int col = ct * 16 + (l & 15);
            W1p[idx] = (f16)W1[k * F1 + col];
        } else {
            int i2 = idx - 32768;         // < 16384
            int j = i2 & 7, l = (i2 >> 3) & 63, fi = i2 >> 9;
            int kb = fi & 7, ct = fi >> 3;
            int k = kb * 32 + (l >> 4) * 8 + j;
            int col = ct * 16 + (l & 15);
            W2p[i2] = (f16)W2[k * OUTD + col];
        }
    }
}

// ===== CSR pass 2: per-row exclusive scan, COALESCED (1 block/row) =========
// Restored as a separate dispatch: the round-6 fold into k_part made 196
// blocks each re-read the 150KB matrix with 784B-strided loads (uncoalesced).
__global__ void k_scanR(int* __restrict__ blkhist, int* __restrict__ rowtot)
{
    __shared__ int sh[256];
    const int q = blockIdx.x, t = threadIdx.x;
    int v = (t < PB) ? blkhist[q * PB + t] : 0;
    sh[t] = v; __syncthreads();
    for (int off = 1; off < 256; off <<= 1) {
        int tv = (t >= off) ? sh[t - off] : 0;
        __syncthreads();
        sh[t] += tv;
        __syncthreads();
    }
    if (t < PB) blkhist[q * PB + t] = sh[t] - v;
    if (t == 255) rowtot[q] = sh[255];
}

// ===== CSR pass 3: deterministic partition into bucket-ordered staging ======
__global__ void k_part(const int* __restrict__ ei, const int* __restrict__ blkhist,
                       const int* __restrict__ rowtot, unsigned* __restrict__ staged)
{
    const int b = blockIdx.x, t = threadIdx.x;
    __shared__ int sS[256];
    __shared__ int cur[NB];
    int v = (t < NB) ? rowtot[t] : 0;
    sS[t] = v; __syncthreads();
    for (int off = 1; off < 256; off <<= 1) {
        int tv = (t >= off) ? sS[t - off] : 0;
        __syncthreads();
        sS[t] += tv;
        __syncthreads();
    }
    if (t < NB) cur[t] = (sS[t] - v) + blkhist[t * PB + b];  // S[q] + rowexcl
    __syncthreads();
    const int e0 = b * EPB;
    const int eend = min(e0 + EPB, NEDGE);
    for (int i = e0 + t; i < eend; i += 256) {
        int sN = ei[i];
        int d  = ei[NEDGE + i];
        int pos = atomicAdd(&cur[d >> 8], 1);       // LDS atomic
        staged[pos] = (unsigned)sN | ((unsigned)(d & 255) << 16);
    }
}

// ===== FUSED pass 4 + layer-1 GEMM (src-sort removed: round-4 A/B null) =====
__global__ __launch_bounds__(256) void k_bg(
    const unsigned* __restrict__ staged, const int* __restrict__ rowtot,
    int* __restrict__ row_ptr, int* __restrict__ csr_src,
    const float* __restrict__ x, const f16* __restrict__ W1p,
    const float* __restrict__ as1, const float* __restrict__ ad1,
    f16* __restrict__ xp1h, float* __restrict__ ssrc, float* __restrict__ sdst)
{
    if (blockIdx.x < NB) {
        __shared__ int cnt[256];
        __shared__ int sh[256];
        __shared__ int ssum[4];
        const int q = blockIdx.x, t = threadIdx.x;
        const int wv = t >> 6, lane = t & 63;
        int pv = (t < q) ? rowtot[t] : 0;
#pragma unroll
        for (int off = 32; off; off >>= 1) pv += __shfl_xor(pv, off);
        if (lane == 0) ssum[wv] = pv;
        cnt[t] = 0;
        __syncthreads();
        const int estart = ssum[0] + ssum[1] + ssum[2] + ssum[3];
        const int eend   = estart + rowtot[q];
        const int nodebase = q * 256;
        const int nn = min(256, NODES - nodebase);
        const int csrbase = estart + nodebase;

        for (int i = estart + t; i < eend; i += 256)
            atomicAdd(&cnt[staged[i] >> 16], 1);
        __syncthreads();
        int v = cnt[t];
        sh[t] = v;
        __syncthreads();
        for (int off = 1; off < 256; off <<= 1) {
            int tv = (t >= off) ? sh[t - off] : 0;
            __syncthreads();
            sh[t] += tv;
            __syncthreads();
        }
        int excl = sh[t] - v;
        __syncthreads();
        if (t < nn) {
            int r = csrbase + excl + t;
            row_ptr[nodebase + t] = r;
            csr_src[r] = nodebase + t;      // self-loop in slot 0
            cnt[t] = excl + t + 1;
        }
        __syncthreads();
        for (int i = estart + t; i < eend; i += 256) {
            unsigned u = staged[i];
            int pos = atomicAdd(&cnt[u >> 16], 1);
            csr_src[csrbase + pos] = (int)(u & 0xFFFFu);
        }
        if (q == NB - 1 && t == 0) row_ptr[NODES] = NE2;
        return;
    }

    // ---- gemm1 path ----
    const int wv = threadIdx.x >> 6, lane = threadIdx.x & 63;
    const int l15 = lane & 15, quad = lane >> 4;
    const int rowtile = (blockIdx.x - NB) * 4 + wv;
    if (rowtile >= MTILES) return;
    const int rowbase = rowtile * 16;

    f16x8 afrag[4];
    const float* xrow = x + (rowbase + l15) * INDIM + quad * 8;
#pragma unroll
    for (int kb = 0; kb < 4; ++kb) {
        float4 u0 = *(const float4*)(xrow + kb * 32);
        float4 u1 = *(const float4*)(xrow + kb * 32 + 4);
        f16x8 a;
        a[0] = (f16)u0.x; a[1] = (f16)u0.y; a[2] = (f16)u0.z; a[3] = (f16)u0.w;
        a[4] = (f16)u1.x; a[5] = (f16)u1.y; a[6] = (f16)u1.z; a[7] = (f16)u1.w;
        afrag[kb] = a;
    }

    const f16x8* Wf = (const f16x8*)W1p;
    f32x4 acc[16];
#pragma unroll
    for (int ct = 0; ct < 16; ++ct) acc[ct] = (f32x4){0.f, 0.f, 0.f, 0.f};
#pragma unroll
    for (int ct = 0; ct < 16; ++ct) {
#pragma unroll
        for (int kb = 0; kb < 4; ++kb) {
            f16x8 b = Wf[(ct * 4 + kb) * 64 + lane];
            acc[ct] = __builtin_amdgcn_mfma_f32_16x16x32_f16(afrag[kb], b, acc[ct], 0, 0, 0);
        }
    }
    const int orow = rowbase + quad * 4;
#pragma unroll
    for (int ct = 0; ct < 16; ++ct) {
#pragma unroll
        for (int r = 0; r < 4; ++r)
            xp1h[(orow + r) * F1 + ct * 16 + l15] = (f16)acc[ct][r];
    }
    float ps[4][4], pd[4][4];
#pragma unroll
    for (int h = 0; h < 4; ++h)
#pragma unroll
        for (int r = 0; r < 4; ++r) { ps[h][r] = 0.f; pd[h][r] = 0.f; }
#pragma unroll
    for (int ct = 0; ct < 16; ++ct) {
        float av = as1[ct * 16 + l15];
        float dv = ad1[ct * 16 + l15];
        int h = ct >> 2;
#pragma unroll
        for (int r = 0; r < 4; ++r) {
            ps[h][r] = fmaf(acc[ct][r], av, ps[h][r]);
            pd[h][r] = fmaf(acc[ct][r], dv, pd[h][r]);
        }
    }
#pragma unroll
    for (int off = 8; off; off >>= 1) {
#pragma unroll
        for (int h = 0; h < 4; ++h)
#pragma unroll
            for (int r = 0; r < 4; ++r) {
                ps[h][r] += __shfl_xor(ps[h][r], off);
                pd[h][r] += __shfl_xor(pd[h][r], off);
            }
    }
    if (l15 == 0) {
#pragma unroll
        for (int r = 0; r < 4; ++r) {
            int row = orow + r;
            float4 vs = {ps[0][r], ps[1][r], ps[2][r], ps[3][r]};
            float4 vd = {pd[0][r], pd[1][r], pd[2][r], pd[3][r]};
            ((float4*)ssrc)[row] = vs;
            ((float4*)sdst)[row] = vd;
        }
    }
}

// ===== Layer 1 aggregate: shuffle-free, 4 edges in flight per group ========
// 4 groups x 16 lanes; group g owns edges e, e+4, e+8, e+12 (stride 16).
// Mean degree ~17 -> most nodes complete in ONE trip with 4 gathers
// outstanding (vs 2x2 before). float4 score load: 1 load + selects.
__global__ __launch_bounds__(256) void k_agg1(
    const int* __restrict__ row_ptr, const int* __restrict__ csr_src,
    const float* __restrict__ ssrc, const float* __restrict__ sdst,
    const f16* __restrict__ xp1h, const float* __restrict__ bias,
    f16* __restrict__ hbuf)
{
    const int wv = threadIdx.x >> 6, l = threadIdx.x & 63;
    const int n = blockIdx.x * 4 + wv;
    const int g = l >> 4, sub = l & 15;
    const int hlo = sub >> 3;                  // lo head 0/1; hi head 2/3
    const float sdl = sdst[n * HEADS + hlo];
    const float sdh = sdst[n * HEADS + 2 + hlo];
    const int jbeg = row_ptr[n], jend = row_ptr[n + 1];
    const f16x8* xv = (const f16x8*)xp1h;
    const float4* sv = (const float4*)ssrc;    // all 4 heads of node s

    float denl = 0.f, denh = 0.f;
    float alo[8] = {0.f,0.f,0.f,0.f,0.f,0.f,0.f,0.f};
    float ahi[8] = {0.f,0.f,0.f,0.f,0.f,0.f,0.f,0.f};

    for (int e = jbeg + g; e < jend; e += 16) {
        const int e1 = e + 4, e2 = e + 8, e3 = e + 12;
        const bool v1 = e1 < jend, v2 = e2 < jend, v3 = e3 < jend;
        int s0 = csr_src[e];
        int s1 = v1 ? csr_src[e1] : 0;
        int s2 = v2 ? csr_src[e2] : 0;
        int s3 = v3 ? csr_src[e3] : 0;
        float4 q0 = sv[s0];
        float4 q1 = sv[s1];
        float4 q2 = sv[s2];
        float4 q3 = sv[s3];
        f16x8 w0l = xv[s0 * 32 + sub], w0h = xv[s0 * 32 + sub + 16];
        f16x8 w1l = xv[s1 * 32 + sub], w1h = xv[s1 * 32 + sub + 16];
        f16x8 w2l = xv[s2 * 32 + sub], w2h = xv[s2 * 32 + sub + 16];
        f16x8 w3l = xv[s3 * 32 + sub], w3h = xv[s3 * 32 + sub + 16];
        float x0l = lrelu_exp((hlo ? q0.y : q0.x) + sdl);
        float x0h = lrelu_exp((hlo ? q0.w : q0.z) + sdh);
        float x1l = v1 ? lrelu_exp((hlo ? q1.y : q1.x) + sdl) : 0.f;
        float x1h = v1 ? lrelu_exp((hlo ? q1.w : q1.z) + sdh) : 0.f;
        float x2l = v2 ? lrelu_exp((hlo ? q2.y : q2.x) + sdl) : 0.f;
        float x2h = v2 ? lrelu_exp((hlo ? q2.w : q2.z) + sdh) : 0.f;
        float x3l = v3 ? lrelu_exp((hlo ? q3.y : q3.x) + sdl) : 0.f;
        float x3h = v3 ? lrelu_exp((hlo ? q3.w : q3.z) + sdh) : 0.f;
        denl += (x0l + x1l) + (x2l + x3l);
        denh += (x0h + x1h) + (x2h + x3h);
#pragma unroll
        for (int j = 0; j < 8; ++j) {
            alo[j] = fmaf(x0l, (float)w0l[j], alo[j]);
            ahi[j] = fmaf(x0h, (float)w0h[j], ahi[j]);
        }
#pragma unroll
        for (int j = 0; j < 8; ++j) {
            alo[j] = fmaf(x1l, (float)w1l[j], alo[j]);
            ahi[j] = fmaf(x1h, (float)w1h[j], ahi[j]);
        }
#pragma unroll
        for (int j = 0; j < 8; ++j) {
            alo[j] = fmaf(x2l, (float)w2l[j], alo[j]);
            ahi[j] = fmaf(x2h, (float)w2h[j], ahi[j]);
        }
#pragma unroll
        for (int j = 0; j < 8; ++j) {
            alo[j] = fmaf(x3l, (float)w3l[j], alo[j]);
            ahi[j] = fmaf(x3h, (float)w3h[j], ahi[j]);
        }
    }
    // sum the 4 edge-groups (lane bits 4,5)
    denl += __shfl_xor(denl, 16); denl += __shfl_xor(denl, 32);
    denh += __shfl_xor(denh, 16); denh += __shfl_xor(denh, 32);
    const float rdl = 1.f / (denl + 1e-16f);
    const float rdh = 1.f / (denh + 1e-16f);
#pragma unroll
    for (int j = 0; j < 8; ++j) {
        alo[j] += __shfl_xor(alo[j], 16); alo[j] += __shfl_xor(alo[j], 32);
        ahi[j] += __shfl_xor(ahi[j], 16); ahi[j] += __shfl_xor(ahi[j], 32);
    }
    if (g == 0) {
        const float4* b4 = (const float4*)bias;
        float4 bl0 = b4[sub * 2],        bl1 = b4[sub * 2 + 1];
        float4 bh0 = b4[(sub + 16) * 2], bh1 = b4[(sub + 16) * 2 + 1];
        f16x8 olo, ohi;
        float v;
        v = fmaf(alo[0], rdl, bl0.x); olo[0] = (f16)(v > 0.f ? v : 0.f);
        v = fmaf(alo[1], rdl, bl0.y); olo[1] = (f16)(v > 0.f ? v : 0.f);
        v = fmaf(alo[2], rdl, bl0.z); olo[2] = (f16)(v > 0.f ? v : 0.f);
        v = fmaf(alo[3], rdl, bl0.w); olo[3] = (f16)(v > 0.f ? v : 0.f);
        v = fmaf(alo[4], rdl, bl1.x); olo[4] = (f16)(v > 0.f ? v : 0.f);
        v = fmaf(alo[5], rdl, bl1.y); olo[5] = (f16)(v > 0.f ? v : 0.f);
        v = fmaf(alo[6], rdl, bl1.z); olo[6] = (f16)(v > 0.f ? v : 0.f);
        v = fmaf(alo[7], rdl, bl1.w); olo[7] = (f16)(v > 0.f ? v : 0.f);
        v = fmaf(ahi[0], rdh, bh0.x); ohi[0] = (f16)(v > 0.f ? v : 0.f);
        v = fmaf(ahi[1], rdh, bh0.y); ohi[1] = (f16)(v > 0.f ? v : 0.f);
        v = fmaf(ahi[2], rdh, bh0.z); ohi[2] = (f16)(v > 0.f ? v : 0.f);
        v = fmaf(ahi[3], rdh, bh0.w); ohi[3] = (f16)(v > 0.f ? v : 0.f);
        v = fmaf(ahi[4], rdh, bh1.x); ohi[4] = (f16)(v > 0.f ? v : 0.f);
        v = fmaf(ahi[5], rdh, bh1.y); ohi[5] = (f16)(v > 0.f ? v : 0.f);
        v = fmaf(ahi[6], rdh, bh1.z); ohi[6] = (f16)(v > 0.f ? v : 0.f);
        v = fmaf(ahi[7], rdh, bh1.w); ohi[7] = (f16)(v > 0.f ? v : 0.f);
        ((f16x8*)hbuf)[n * 32 + sub] = olo;
        ((f16x8*)hbuf)[n * 32 + sub + 16] = ohi;
    }
}

// ====== Layer 2 GEMM (MFMA) + fused scores ================================
__global__ __launch_bounds__(256) void k_gemm2m(
    const f16* __restrict__ hbuf, const f16* __restrict__ W2p,
    const float* __restrict__ as2, const float* __restrict__ ad2,
    f16* __restrict__ xp2h, float* __restrict__ ssrc, float* __restrict__ sdst)
{
    const int wv = threadIdx.x >> 6, lane = threadIdx.x & 63;
    const int l15 = lane & 15, quad = lane >> 4;
    const int rowtile = blockIdx.x * 4 + wv;
    if (rowtile >= MTILES) return;
    const int rowbase = rowtile * 16;

    const f16x8* Wf = (const f16x8*)W2p;
    f32x4 acc[4];
#pragma unroll
    for (int ct = 0; ct < 4; ++ct) acc[ct] = (f32x4){0.f, 0.f, 0.f, 0.f};
    const f16* hrow = hbuf + (rowbase + l15) * F1 + quad * 8;
#pragma unroll
    for (int kb = 0; kb < 8; ++kb) {
        f16x8 a = *(const f16x8*)(hrow + kb * 32);
#pragma unroll
        for (int ct = 0; ct < 4; ++ct) {
            f16x8 b = Wf[(ct * 8 + kb) * 64 + lane];
            acc[ct] = __builtin_amdgcn_mfma_f32_16x16x32_f16(a, b, acc[ct], 0, 0, 0);
        }
    }
    const int orow = rowbase + quad * 4;
#pragma unroll
    for (int ct = 0; ct < 4; ++ct) {
#pragma unroll
        for (int r = 0; r < 4; ++r)
            xp2h[(orow + r) * OUTD + ct * 16 + l15] = (f16)acc[ct][r];
    }
    float ps[4] = {0.f,0.f,0.f,0.f}, pd[4] = {0.f,0.f,0.f,0.f};
#pragma unroll
    for (int ct = 0; ct < 4; ++ct) {
        float av = as2[ct * 16 + l15];
        float dv = ad2[ct * 16 + l15];
#pragma unroll
        for (int r = 0; r < 4; ++r) {
            ps[r] = fmaf(acc[ct][r], av, ps[r]);
            pd[r] = fmaf(acc[ct][r], dv, pd[r]);
        }
    }
#pragma unroll
    for (int off = 8; off; off >>= 1) {
#pragma unroll
        for (int r = 0; r < 4; ++r) {
            ps[r] += __shfl_xor(ps[r], off);
            pd[r] += __shfl_xor(pd[r], off);
        }
    }
    if (l15 == 0) {
#pragma unroll
        for (int r = 0; r < 4; ++r) {
            ssrc[orow + r] = ps[r];
            sdst[orow + r] = pd[r];
        }
    }
}

// ===== Layer 2 aggregate: shuffle-free, 4 edges in flight per group ========
// 8 groups x 8 lanes; group owns edges e, e+8, e+16, e+24 (stride 32).
__global__ __launch_bounds__(256) void k_agg2(
    const int* __restrict__ row_ptr, const int* __restrict__ csr_src,
    const float* __restrict__ ssrc, const float* __restrict__ sdst,
    const f16* __restrict__ xp2h, const float* __restrict__ bias,
    float* __restrict__ out)
{
    const int wv = threadIdx.x >> 6, l = threadIdx.x & 63;
    const int n = blockIdx.x * 4 + wv;
    const int grp = l >> 3, sub = l & 7;
    const float sd = sdst[n];
    const int jbeg = row_ptr[n], jend = row_ptr[n + 1];
    const f16x8* xv = (const f16x8*)xp2h;

    float den = 0.f;
    float acc[8] = {0.f,0.f,0.f,0.f,0.f,0.f,0.f,0.f};
    for (int e = jbeg + grp; e < jend; e += 32) {
        const int e1 = e + 8, e2 = e + 16, e3 = e + 24;
        const bool v1 = e1 < jend, v2 = e2 < jend, v3 = e3 < jend;
        int s0 = csr_src[e];
        int s1 = v1 ? csr_src[e1] : 0;
        int s2 = v2 ? csr_src[e2] : 0;
        int s3 = v3 ? csr_src[e3] : 0;
        float c0 = ssrc[s0];
        float c1 = ssrc[s1];
        float c2 = ssrc[s2];
        float c3 = ssrc[s3];
        f16x8 w0 = xv[s0 * 8 + sub];
        f16x8 w1 = xv[s1 * 8 + sub];
        f16x8 w2 = xv[s2 * 8 + sub];
        f16x8 w3 = xv[s3 * 8 + sub];
        float x0 = lrelu_exp(c0 + sd);
        float x1 = v1 ? lrelu_exp(c1 + sd) : 0.f;
        float x2 = v2 ? lrelu_exp(c2 + sd) : 0.f;
        float x3 = v3 ? lrelu_exp(c3 + sd) : 0.f;
        den += (x0 + x1) + (x2 + x3);
#pragma unroll
        for (int j = 0; j < 8; ++j) acc[j] = fmaf(x0, (float)w0[j], acc[j]);
#pragma unroll
        for (int j = 0; j < 8; ++j) acc[j] = fmaf(x1, (float)w1[j], acc[j]);
#pragma unroll
        for (int j = 0; j < 8; ++j) acc[j] = fmaf(x2, (float)w2[j], acc[j]);
#pragma unroll
        for (int j = 0; j < 8; ++j) acc[j] = fmaf(x3, (float)w3[j], acc[j]);
    }
    den += __shfl_xor(den, 8);
    den += __shfl_xor(den, 16);
    den += __shfl_xor(den, 32);
    const float rd = 1.f / (den + 1e-16f);
#pragma unroll
    for (int j = 0; j < 8; ++j) {
        acc[j] += __shfl_xor(acc[j], 8);
        acc[j] += __shfl_xor(acc[j], 16);
        acc[j] += __shfl_xor(acc[j], 32);
    }
    if (grp == 0) {
        const float4* b4 = (const float4*)bias;
        float4 ba = b4[sub * 2], bb = b4[sub * 2 + 1];
        float4 o0, o1;
        o0.x = fmaf(acc[0], rd, ba.x); o0.y = fmaf(acc[1], rd, ba.y);
        o0.z = fmaf(acc[2], rd, ba.z); o0.w = fmaf(acc[3], rd, ba.w);
        o1.x = fmaf(acc[4], rd, bb.x); o1.y = fmaf(acc[5], rd, bb.y);
        o1.z = fmaf(acc[6], rd, bb.z); o1.w = fmaf(acc[7], rd, bb.w);
        float4* ov = (float4*)out + n * 16 + sub * 2;
        ov[0] = o0; ov[1] = o1;
    }
}

extern "C" void kernel_launch(void* const* d_in, const int* in_sizes, int n_in,
                              void* d_out, int out_size, void* d_ws, size_t ws_size,
                              hipStream_t stream)
{
    (void)in_sizes; (void)n_in; (void)out_size; (void)ws_size;
    const float* x   = (const float*)d_in[0];
    const int*   ei  = (const int*)d_in[1];
    const float* W1  = (const float*)d_in[2];
    const float* as1 = (const float*)d_in[3];
    const float* ad1 = (const float*)d_in[4];
    const float* b1  = (const float*)d_in[5];
    const float* W2  = (const float*)d_in[6];
    const float* as2 = (const float*)d_in[7];
    const float* ad2 = (const float*)d_in[8];
    const float* b2  = (const float*)d_in[9];
    float* out = (float*)d_out;

    // workspace layout (~61 MB)
    f16* xp1h    = (f16*)d_ws;                             // N*256 f16 (25.6 MB)
    f16* hbuf    = xp1h + (size_t)NODES * F1;              // N*256 f16 (25.6 MB)
    f16* W1p     = hbuf + (size_t)NODES * F1;              // 32768 f16
    f16* W2p     = W1p + 32768;                            // 16384 f16
    float* ssrc1 = (float*)(W2p + 16384);                  // N*4
    float* sdst1 = ssrc1 + (size_t)NODES * HEADS;          // N*4
    float* ssrc2 = sdst1 + (size_t)NODES * HEADS;          // N
    float* sdst2 = ssrc2 + (size_t)NODES;                  // N
    int* row_ptr = (int*)(sdst2 + (size_t)NODES);          // N+1
    int* blkhist = row_ptr + NODES + 1;                    // NB*PB = 38416
    int* rowtot  = blkhist + NB * PB;                      // NB
    int* csr_src = rowtot + NB;                            // NE2
    unsigned* staged = (unsigned*)(csr_src + NE2);         // NEDGE (3.2 MB)
    f16* xp2h    = xp1h;   // alias: xp1h dead after k_agg1

    // ---- CSR build: bucketed counting sort, zero global atomics ----
    k_hist<<<PB + 192, 256, 0, stream>>>(ei, blkhist, W1, W2, W1p, W2p);
    k_scanR<<<NB, 256, 0, stream>>>(blkhist, rowtot);
    k_part<<<PB, 256, 0, stream>>>(ei, blkhist, rowtot, staged);

    // ---- fused: bucket CSR-finish || layer-1 GEMM ----
    k_bg<<<NB + G1B, 256, 0, stream>>>(staged, rowtot, row_ptr, csr_src,
                                       x, W1p, as1, ad1, xp1h, ssrc1, sdst1);

    // ---- layer 1 aggregate (4-deep MLP) ----
    k_agg1<<<NODES / 4, 256, 0, stream>>>(row_ptr, csr_src, ssrc1, sdst1,
                                          xp1h, b1, hbuf);

    // ---- layer 2 ----
    k_gemm2m<<<(MTILES + 3) / 4, 256, 0, stream>>>(hbuf, W2p, as2, ad2,
                                                   xp2h, ssrc2, sdst2);
    k_agg2<<<NODES / 4, 256, 0, stream>>>(row_ptr, csr_src, ssrc2, sdst2,
                                          xp2h, b2, out);
}

// Round 11
// 224.652 us; speedup vs baseline: 1.6546x; 1.0172x over previous
//
#include <hip/hip_runtime.h>
#include <hip/hip_bf16.h>
#include <hip/hip_fp16.h>

// Problem constants (from reference)
#define NODES 50000
#define NEDGE 800000
#define NE2   850000   // NEDGE + NODES self-loops
#define INDIM 128
#define F1    256      // HEADS*HID
#define HEADS 4
#define HID   64
#define OUTD  64
#define MTILES 3125    // NODES/16

// Bucketed CSR build (no global atomics)
#define NB   196       // buckets = ceil(NODES/256)
#define PB   196       // partition blocks
#define EPB  4096      // edges per partition block
#define G1B  782       // ceil(MTILES/4) gemm1 blocks in fused k_bg

typedef _Float16 f16;
typedef _Float16 f16x8 __attribute__((ext_vector_type(8)));
typedef float    f32x4 __attribute__((ext_vector_type(4)));

__device__ __forceinline__ float lrelu_exp(float e) {
    e = e > 0.f ? e : 0.2f * e;
    return __expf(e);
}

// ===== CSR pass 1: per-block LDS bucket histogram (+ W pre-swizzle blocks) ==
__global__ void k_hist(const int* __restrict__ ei, int* __restrict__ blkhist,
                       const float* __restrict__ W1, const float* __restrict__ W2,
                       f16* __restrict__ W1p, f16* __restrict__ W2p)
{
    const int b = blockIdx.x, t = threadIdx.x;
    if (b < PB) {
        __shared__ int h[NB];
        for (int i = t; i < NB; i += 256) h[i] = 0;
        __syncthreads();
        const int e0 = b * EPB;
        const int eend = min(e0 + EPB, NEDGE);
        for (int i = e0 + t; i < eend; i += 256) {
            int d = ei[NEDGE + i];
            atomicAdd(&h[d >> 8], 1);
        }
        __syncthreads();
        // [bucket][block] layout (RAW counts)
        for (int i = t; i < NB; i += 256) blkhist[i * PB + b] = h[i];
    } else {
        int idx = (b - PB) * 256 + t;     // < 49152
        if (idx < 32768) {
            int j = idx & 7, l = (idx >> 3) & 63, fi = idx >> 9;
            int kb = fi & 3, ct = fi >> 2;
            int k = kb * 32 + (l >> 4) * 8 + j;
            int col = ct * 16 + (l & 15);
            W1p[idx] = (f16)W1[k * F1 + col];
        } else {
            int i2 = idx - 32768;         // < 16384
            int j = i2 & 7, l = (i2 >> 3) & 63, fi = i2 >> 9;
            int kb = fi & 7, ct = fi >> 3;
            int k = kb * 32 + (l >> 4) * 8 + j;
            int col = ct * 16 + (l & 15);
            W2p[i2] = (f16)W2[k * OUTD + col];
        }
    }
}

// ===== CSR pass 2: per-row exclusive scan, COALESCED (1 block/row) =========
__global__ void k_scanR(int* __restrict__ blkhist, int* __restrict__ rowtot)
{
    __shared__ int sh[256];
    const int q = blockIdx.x, t = threadIdx.x;
    int v = (t < PB) ? blkhist[q * PB + t] : 0;
    sh[t] = v; __syncthreads();
    for (int off = 1; off < 256; off <<= 1) {
        int tv = (t >= off) ? sh[t - off] : 0;
        __syncthreads();
        sh[t] += tv;
        __syncthreads();
    }
    if (t < PB) blkhist[q * PB + t] = sh[t] - v;
    if (t == 255) rowtot[q] = sh[255];
}

// ===== CSR pass 3: deterministic partition into bucket-ordered staging ======
__global__ void k_part(const int* __restrict__ ei, const int* __restrict__ blkhist,
                       const int* __restrict__ rowtot, unsigned* __restrict__ staged)
{
    const int b = blockIdx.x, t = threadIdx.x;
    __shared__ int sS[256];
    __shared__ int cur[NB];
    int v = (t < NB) ? rowtot[t] : 0;
    sS[t] = v; __syncthreads();
    for (int off = 1; off < 256; off <<= 1) {
        int tv = (t >= off) ? sS[t - off] : 0;
        __syncthreads();
        sS[t] += tv;
        __syncthreads();
    }
    if (t < NB) cur[t] = (sS[t] - v) + blkhist[t * PB + b];  // S[q] + rowexcl
    __syncthreads();
    const int e0 = b * EPB;
    const int eend = min(e0 + EPB, NEDGE);
    for (int i = e0 + t; i < eend; i += 256) {
        int sN = ei[i];
        int d  = ei[NEDGE + i];
        int pos = atomicAdd(&cur[d >> 8], 1);       // LDS atomic
        staged[pos] = (unsigned)sN | ((unsigned)(d & 255) << 16);
    }
}

// ===== FUSED pass 4 + layer-1 GEMM =========================================
__global__ __launch_bounds__(256) void k_bg(
    const unsigned* __restrict__ staged, const int* __restrict__ rowtot,
    int* __restrict__ row_ptr, int* __restrict__ csr_src,
    const float* __restrict__ x, const f16* __restrict__ W1p,
    const float* __restrict__ as1, const float* __restrict__ ad1,
    f16* __restrict__ xp1h, float* __restrict__ ssrc, float* __restrict__ sdst)
{
    if (blockIdx.x < NB) {
        __shared__ int cnt[256];
        __shared__ int sh[256];
        __shared__ int ssum[4];
        const int q = blockIdx.x, t = threadIdx.x;
        const int wv = t >> 6, lane = t & 63;
        int pv = (t < q) ? rowtot[t] : 0;
#pragma unroll
        for (int off = 32; off; off >>= 1) pv += __shfl_xor(pv, off);
        if (lane == 0) ssum[wv] = pv;
        cnt[t] = 0;
        __syncthreads();
        const int estart = ssum[0] + ssum[1] + ssum[2] + ssum[3];
        const int eend   = estart + rowtot[q];
        const int nodebase = q * 256;
        const int nn = min(256, NODES - nodebase);
        const int csrbase = estart + nodebase;

        for (int i = estart + t; i < eend; i += 256)
            atomicAdd(&cnt[staged[i] >> 16], 1);
        __syncthreads();
        int v = cnt[t];
        sh[t] = v;
        __syncthreads();
        for (int off = 1; off < 256; off <<= 1) {
            int tv = (t >= off) ? sh[t - off] : 0;
            __syncthreads();
            sh[t] += tv;
            __syncthreads();
        }
        int excl = sh[t] - v;
        __syncthreads();
        if (t < nn) {
            int r = csrbase + excl + t;
            row_ptr[nodebase + t] = r;
            csr_src[r] = nodebase + t;      // self-loop in slot 0
            cnt[t] = excl + t + 1;
        }
        __syncthreads();
        for (int i = estart + t; i < eend; i += 256) {
            unsigned u = staged[i];
            int pos = atomicAdd(&cnt[u >> 16], 1);
            csr_src[csrbase + pos] = (int)(u & 0xFFFFu);
        }
        if (q == NB - 1 && t == 0) row_ptr[NODES] = NE2;
        return;
    }

    // ---- gemm1 path ----
    const int wv = threadIdx.x >> 6, lane = threadIdx.x & 63;
    const int l15 = lane & 15, quad = lane >> 4;
    const int rowtile = (blockIdx.x - NB) * 4 + wv;
    if (rowtile >= MTILES) return;
    const int rowbase = rowtile * 16;

    f16x8 afrag[4];
    const float* xrow = x + (rowbase + l15) * INDIM + quad * 8;
#pragma unroll
    for (int kb = 0; kb < 4; ++kb) {
        float4 u0 = *(const float4*)(xrow + kb * 32);
        float4 u1 = *(const float4*)(xrow + kb * 32 + 4);
        f16x8 a;
        a[0] = (f16)u0.x; a[1] = (f16)u0.y; a[2] = (f16)u0.z; a[3] = (f16)u0.w;
        a[4] = (f16)u1.x; a[5] = (f16)u1.y; a[6] = (f16)u1.z; a[7] = (f16)u1.w;
        afrag[kb] = a;
    }

    const f16x8* Wf = (const f16x8*)W1p;
    f32x4 acc[16];
#pragma unroll
    for (int ct = 0; ct < 16; ++ct) acc[ct] = (f32x4){0.f, 0.f, 0.f, 0.f};
#pragma unroll
    for (int ct = 0; ct < 16; ++ct) {
#pragma unroll
        for (int kb = 0; kb < 4; ++kb) {
            f16x8 b = Wf[(ct * 4 + kb) * 64 + lane];
            acc[ct] = __builtin_amdgcn_mfma_f32_16x16x32_f16(afrag[kb], b, acc[ct], 0, 0, 0);
        }
    }
    const int orow = rowbase + quad * 4;
#pragma unroll
    for (int ct = 0; ct < 16; ++ct) {
#pragma unroll
        for (int r = 0; r < 4; ++r)
            xp1h[(orow + r) * F1 + ct * 16 + l15] = (f16)acc[ct][r];
    }
    float ps[4][4], pd[4][4];
#pragma unroll
    for (int h = 0; h < 4; ++h)
#pragma unroll
        for (int r = 0; r < 4; ++r) { ps[h][r] = 0.f; pd[h][r] = 0.f; }
#pragma unroll
    for (int ct = 0; ct < 16; ++ct) {
        float av = as1[ct * 16 + l15];
        float dv = ad1[ct * 16 + l15];
        int h = ct >> 2;
#pragma unroll
        for (int r = 0; r < 4; ++r) {
            ps[h][r] = fmaf(acc[ct][r], av, ps[h][r]);
            pd[h][r] = fmaf(acc[ct][r], dv, pd[h][r]);
        }
    }
#pragma unroll
    for (int off = 8; off; off >>= 1) {
#pragma unroll
        for (int h = 0; h < 4; ++h)
#pragma unroll
            for (int r = 0; r < 4; ++r) {
                ps[h][r] += __shfl_xor(ps[h][r], off);
                pd[h][r] += __shfl_xor(pd[h][r], off);
            }
    }
    if (l15 == 0) {
#pragma unroll
        for (int r = 0; r < 4; ++r) {
            int row = orow + r;
            float4 vs = {ps[0][r], ps[1][r], ps[2][r], ps[3][r]};
            float4 vd = {pd[0][r], pd[1][r], pd[2][r], pd[3][r]};
            ((float4*)ssrc)[row] = vs;
            ((float4*)sdst)[row] = vd;
        }
    }
}

// ===== Layer 1 aggregate: shuffle-free, 2 edges in flight (round-8 best) ===
// 4 groups x 16 lanes; each lane loads edge metadata directly (group-uniform
// csr load coalesces; score gather = 1 line/edge); no cross-lane ops in loop.
__global__ __launch_bounds__(256) void k_agg1(
    const int* __restrict__ row_ptr, const int* __restrict__ csr_src,
    const float* __restrict__ ssrc, const float* __restrict__ sdst,
    const f16* __restrict__ xp1h, const float* __restrict__ bias,
    f16* __restrict__ hbuf)
{
    const int wv = threadIdx.x >> 6, l = threadIdx.x & 63;
    const int n = blockIdx.x * 4 + wv;
    const int g = l >> 4, sub = l & 15;
    const int hlo = sub >> 3;                  // lo head: 0/1; hi head: 2/3
    const float sdl = sdst[n * HEADS + hlo];
    const float sdh = sdst[n * HEADS + 2 + hlo];
    const int jbeg = row_ptr[n], jend = row_ptr[n + 1];
    const f16x8* xv = (const f16x8*)xp1h;

    float denl = 0.f, denh = 0.f;
    float alo[8] = {0.f,0.f,0.f,0.f,0.f,0.f,0.f,0.f};
    float ahi[8] = {0.f,0.f,0.f,0.f,0.f,0.f,0.f,0.f};

    for (int e = jbeg + g; e < jend; e += 8) {
        const int e2 = e + 4;
        const bool vb = (e2 < jend);
        int sa = csr_src[e];
        int sb = vb ? csr_src[e2] : 0;
        float scal = ssrc[sa * HEADS + hlo];
        float scah = ssrc[sa * HEADS + 2 + hlo];
        f16x8 va0 = xv[sa * 32 + sub];
        f16x8 va1 = xv[sa * 32 + sub + 16];
        float scbl = ssrc[sb * HEADS + hlo];
        float scbh = ssrc[sb * HEADS + 2 + hlo];
        f16x8 vb0 = xv[sb * 32 + sub];
        f16x8 vb1 = xv[sb * 32 + sub + 16];
        float eal = lrelu_exp(scal + sdl);
        float eah = lrelu_exp(scah + sdh);
        float ebl = vb ? lrelu_exp(scbl + sdl) : 0.f;
        float ebh = vb ? lrelu_exp(scbh + sdh) : 0.f;
        denl += eal + ebl;
        denh += eah + ebh;
#pragma unroll
        for (int j = 0; j < 8; ++j) {
            alo[j] = fmaf(eal, (float)va0[j], alo[j]);
            ahi[j] = fmaf(eah, (float)va1[j], ahi[j]);
        }
#pragma unroll
        for (int j = 0; j < 8; ++j) {
            alo[j] = fmaf(ebl, (float)vb0[j], alo[j]);
            ahi[j] = fmaf(ebh, (float)vb1[j], ahi[j]);
        }
    }
    // sum the 4 edge-groups (den partials are per-lane per-head already)
    denl += __shfl_xor(denl, 16); denl += __shfl_xor(denl, 32);
    denh += __shfl_xor(denh, 16); denh += __shfl_xor(denh, 32);
    const float rdl = 1.f / (denl + 1e-16f);
    const float rdh = 1.f / (denh + 1e-16f);
#pragma unroll
    for (int j = 0; j < 8; ++j) {
        alo[j] += __shfl_xor(alo[j], 16); alo[j] += __shfl_xor(alo[j], 32);
        ahi[j] += __shfl_xor(ahi[j], 16); ahi[j] += __shfl_xor(ahi[j], 32);
    }
    if (g == 0) {
        const float4* b4 = (const float4*)bias;
        float4 bl0 = b4[sub * 2],        bl1 = b4[sub * 2 + 1];
        float4 bh0 = b4[(sub + 16) * 2], bh1 = b4[(sub + 16) * 2 + 1];
        f16x8 olo, ohi;
        float v;
        v = fmaf(alo[0], rdl, bl0.x); olo[0] = (f16)(v > 0.f ? v : 0.f);
        v = fmaf(alo[1], rdl, bl0.y); olo[1] = (f16)(v > 0.f ? v : 0.f);
        v = fmaf(alo[2], rdl, bl0.z); olo[2] = (f16)(v > 0.f ? v : 0.f);
        v = fmaf(alo[3], rdl, bl0.w); olo[3] = (f16)(v > 0.f ? v : 0.f);
        v = fmaf(alo[4], rdl, bl1.x); olo[4] = (f16)(v > 0.f ? v : 0.f);
        v = fmaf(alo[5], rdl, bl1.y); olo[5] = (f16)(v > 0.f ? v : 0.f);
        v = fmaf(alo[6], rdl, bl1.z); olo[6] = (f16)(v > 0.f ? v : 0.f);
        v = fmaf(alo[7], rdl, bl1.w); olo[7] = (f16)(v > 0.f ? v : 0.f);
        v = fmaf(ahi[0], rdh, bh0.x); ohi[0] = (f16)(v > 0.f ? v : 0.f);
        v = fmaf(ahi[1], rdh, bh0.y); ohi[1] = (f16)(v > 0.f ? v : 0.f);
        v = fmaf(ahi[2], rdh, bh0.z); ohi[2] = (f16)(v > 0.f ? v : 0.f);
        v = fmaf(ahi[3], rdh, bh0.w); ohi[3] = (f16)(v > 0.f ? v : 0.f);
        v = fmaf(ahi[4], rdh, bh1.x); ohi[4] = (f16)(v > 0.f ? v : 0.f);
        v = fmaf(ahi[5], rdh, bh1.y); ohi[5] = (f16)(v > 0.f ? v : 0.f);
        v = fmaf(ahi[6], rdh, bh1.z); ohi[6] = (f16)(v > 0.f ? v : 0.f);
        v = fmaf(ahi[7], rdh, bh1.w); ohi[7] = (f16)(v > 0.f ? v : 0.f);
        ((f16x8*)hbuf)[n * 32 + sub] = olo;
        ((f16x8*)hbuf)[n * 32 + sub + 16] = ohi;
    }
}

// ====== Layer 2 GEMM (MFMA) + fused scores ================================
__global__ __launch_bounds__(256) void k_gemm2m(
    const f16* __restrict__ hbuf, const f16* __restrict__ W2p,
    const float* __restrict__ as2, const float* __restrict__ ad2,
    f16* __restrict__ xp2h, float* __restrict__ ssrc, float* __restrict__ sdst)
{
    const int wv = threadIdx.x >> 6, lane = threadIdx.x & 63;
    const int l15 = lane & 15, quad = lane >> 4;
    const int rowtile = blockIdx.x * 4 + wv;
    if (rowtile >= MTILES) return;
    const int rowbase = rowtile * 16;

    const f16x8* Wf = (const f16x8*)W2p;
    f32x4 acc[4];
#pragma unroll
    for (int ct = 0; ct < 4; ++ct) acc[ct] = (f32x4){0.f, 0.f, 0.f, 0.f};
    const f16* hrow = hbuf + (rowbase + l15) * F1 + quad * 8;
#pragma unroll
    for (int kb = 0; kb < 8; ++kb) {
        f16x8 a = *(const f16x8*)(hrow + kb * 32);
#pragma unroll
        for (int ct = 0; ct < 4; ++ct) {
            f16x8 b = Wf[(ct * 8 + kb) * 64 + lane];
            acc[ct] = __builtin_amdgcn_mfma_f32_16x16x32_f16(a, b, acc[ct], 0, 0, 0);
        }
    }
    const int orow = rowbase + quad * 4;
#pragma unroll
    for (int ct = 0; ct < 4; ++ct) {
#pragma unroll
        for (int r = 0; r < 4; ++r)
            xp2h[(orow + r) * OUTD + ct * 16 + l15] = (f16)acc[ct][r];
    }
    float ps[4] = {0.f,0.f,0.f,0.f}, pd[4] = {0.f,0.f,0.f,0.f};
#pragma unroll
    for (int ct = 0; ct < 4; ++ct) {
        float av = as2[ct * 16 + l15];
        float dv = ad2[ct * 16 + l15];
#pragma unroll
        for (int r = 0; r < 4; ++r) {
            ps[r] = fmaf(acc[ct][r], av, ps[r]);
            pd[r] = fmaf(acc[ct][r], dv, pd[r]);
        }
    }
#pragma unroll
    for (int off = 8; off; off >>= 1) {
#pragma unroll
        for (int r = 0; r < 4; ++r) {
            ps[r] += __shfl_xor(ps[r], off);
            pd[r] += __shfl_xor(pd[r], off);
        }
    }
    if (l15 == 0) {
#pragma unroll
        for (int r = 0; r < 4; ++r) {
            ssrc[orow + r] = ps[r];
            sdst[orow + r] = pd[r];
        }
    }
}

// ===== Layer 2 aggregate: shuffle-free, 2 edges in flight (round-8 best) ===
__global__ __launch_bounds__(256) void k_agg2(
    const int* __restrict__ row_ptr, const int* __restrict__ csr_src,
    const float* __restrict__ ssrc, const float* __restrict__ sdst,
    const f16* __restrict__ xp2h, const float* __restrict__ bias,
    float* __restrict__ out)
{
    const int wv = threadIdx.x >> 6, l = threadIdx.x & 63;
    const int n = blockIdx.x * 4 + wv;
    const int grp = l >> 3, sub = l & 7;
    const float sd = sdst[n];
    const int jbeg = row_ptr[n], jend = row_ptr[n + 1];
    const f16x8* xv = (const f16x8*)xp2h;

    float den = 0.f;
    float acc[8] = {0.f,0.f,0.f,0.f,0.f,0.f,0.f,0.f};
    for (int e = jbeg + grp; e < jend; e += 16) {
        const int e2 = e + 8;
        const bool vb = (e2 < jend);
        int sa = csr_src[e];
        int sb = vb ? csr_src[e2] : 0;
        float sca = ssrc[sa];
        float scb = ssrc[sb];
        f16x8 va = xv[sa * 8 + sub];
        f16x8 vbx = xv[sb * 8 + sub];
        float ea = lrelu_exp(sca + sd);
        float eb = vb ? lrelu_exp(scb + sd) : 0.f;
        den += ea + eb;
#pragma unroll
        for (int j = 0; j < 8; ++j) acc[j] = fmaf(ea, (float)va[j], acc[j]);
#pragma unroll
        for (int j = 0; j < 8; ++j) acc[j] = fmaf(eb, (float)vbx[j], acc[j]);
    }
    den += __shfl_xor(den, 8);
    den += __shfl_xor(den, 16);
    den += __shfl_xor(den, 32);
    const float rd = 1.f / (den + 1e-16f);
#pragma unroll
    for (int j = 0; j < 8; ++j) {
        acc[j] += __shfl_xor(acc[j], 8);
        acc[j] += __shfl_xor(acc[j], 16);
        acc[j] += __shfl_xor(acc[j], 32);
    }
    if (grp == 0) {
        const float4* b4 = (const float4*)bias;
        float4 ba = b4[sub * 2], bb = b4[sub * 2 + 1];
        float4 o0, o1;
        o0.x = fmaf(acc[0], rd, ba.x); o0.y = fmaf(acc[1], rd, ba.y);
        o0.z = fmaf(acc[2], rd, ba.z); o0.w = fmaf(acc[3], rd, ba.w);
        o1.x = fmaf(acc[4], rd, bb.x); o1.y = fmaf(acc[5], rd, bb.y);
        o1.z = fmaf(acc[6], rd, bb.z); o1.w = fmaf(acc[7], rd, bb.w);
        float4* ov = (float4*)out + n * 16 + sub * 2;
        ov[0] = o0; ov[1] = o1;
    }
}

extern "C" void kernel_launch(void* const* d_in, const int* in_sizes, int n_in,
                              void* d_out, int out_size, void* d_ws, size_t ws_size,
                              hipStream_t stream)
{
    (void)in_sizes; (void)n_in; (void)out_size; (void)ws_size;
    const float* x   = (const float*)d_in[0];
    const int*   ei  = (const int*)d_in[1];
    const float* W1  = (const float*)d_in[2];
    const float* as1 = (const float*)d_in[3];
    const float* ad1 = (const float*)d_in[4];
    const float* b1  = (const float*)d_in[5];
    const float* W2  = (const float*)d_in[6];
    const float* as2 = (const float*)d_in[7];
    const float* ad2 = (const float*)d_in[8];
    const float* b2  = (const float*)d_in[9];
    float* out = (float*)d_out;

    // workspace layout (~61 MB)
    f16* xp1h    = (f16*)d_ws;                             // N*256 f16 (25.6 MB)
    f16* hbuf    = xp1h + (size_t)NODES * F1;              // N*256 f16 (25.6 MB)
    f16* W1p     = hbuf + (size_t)NODES * F1;              // 32768 f16
    f16* W2p     = W1p + 32768;                            // 16384 f16
    float* ssrc1 = (float*)(W2p + 16384);                  // N*4
    float* sdst1 = ssrc1 + (size_t)NODES * HEADS;          // N*4
    float* ssrc2 = sdst1 + (size_t)NODES * HEADS;          // N
    float* sdst2 = ssrc2 + (size_t)NODES;                  // N
    int* row_ptr = (int*)(sdst2 + (size_t)NODES);          // N+1
    int* blkhist = row_ptr + NODES + 1;                    // NB*PB = 38416
    int* rowtot  = blkhist + NB * PB;                      // NB
    int* csr_src = rowtot + NB;                            // NE2
    unsigned* staged = (unsigned*)(csr_src + NE2);         // NEDGE (3.2 MB)
    f16* xp2h    = xp1h;   // alias: xp1h dead after k_agg1

    // ---- CSR build: bucketed counting sort, zero global atomics ----
    k_hist<<<PB + 192, 256, 0, stream>>>(ei, blkhist, W1, W2, W1p, W2p);
    k_scanR<<<NB, 256, 0, stream>>>(blkhist, rowtot);
    k_part<<<PB, 256, 0, stream>>>(ei, blkhist, rowtot, staged);

    // ---- fused: bucket CSR-finish || layer-1 GEMM ----
    k_bg<<<NB + G1B, 256, 0, stream>>>(staged, rowtot, row_ptr, csr_src,
                                       x, W1p, as1, ad1, xp1h, ssrc1, sdst1);

    // ---- layer 1 aggregate (round-8 best: 2-deep shuffle-free) ----
    k_agg1<<<NODES / 4, 256, 0, stream>>>(row_ptr, csr_src, ssrc1, sdst1,
                                          xp1h, b1, hbuf);

    // ---- layer 2 ----
    k_gemm2m<<<(MTILES + 3) / 4, 256, 0, stream>>>(hbuf, W2p, as2, ad2,
                                                   xp2h, ssrc2, sdst2);
    k_agg2<<<NODES / 4, 256, 0, stream>>>(row_ptr, csr_src, ssrc2, sdst2,
                                          xp2h, b2, out);
}